// Round 10
// baseline (3180.228 us; speedup 1.0000x reference)
//
#include <hip/hip_runtime.h>

using short8 = __attribute__((ext_vector_type(8))) short;
using f32x4  = __attribute__((ext_vector_type(4))) float;

typedef unsigned short u16;
typedef unsigned int   u32;

#define T_SEQ 256
#define BATCH 64
#define INP   256
#define HID   1024
#define GDIM  4096
#define KC    1280   // HID + INP
#define OUTD  1024

#define NSL   40     // K slices of 32 (32 h + 8 x)
#define NBLK  256
#define DBLK  128    // blocks per direction
#define LDSB  (NSL * 2 * 64 * 8 * 2)   // 81920 bytes dynamic LDS

#define MFMA16(a,b,c) __builtin_amdgcn_mfma_f32_16x16x32_bf16(a,b,c,0,0,0)

__device__ __forceinline__ u16 f2bf(float f){
  union { float f; u32 u; } v; v.f = f;
  u32 r = v.u + 0x7fffu + ((v.u >> 16) & 1u);
  return (u16)(r >> 16);
}
__device__ __forceinline__ float sigm(float x){ return 1.f/(1.f+__expf(-x)); }
__device__ __forceinline__ float tanhf_(float x){ return 1.f - 2.f/(__expf(2.f*x)+1.f); }

// agent-scope (device-coherent, IC-resident) store/load — compiler emits sc1
__device__ __forceinline__ void ag_st_u32(u32* p, u32 v){
  __hip_atomic_store(p, v, __ATOMIC_RELAXED, __HIP_MEMORY_SCOPE_AGENT);
}
__device__ __forceinline__ int ag_ld_i32(const int* p){
  return __hip_atomic_load(p, __ATOMIC_RELAXED, __HIP_MEMORY_SCOPE_AGENT);
}

// quad-perm DPP: 4 gates of one h-col live in one lane-quad
template<int CTRL>
__device__ __forceinline__ float qperm(float v){
  union { float f; int i; } u; u.f = v;
  u.i = __builtin_amdgcn_mov_dpp(u.i, CTRL, 0xf, 0xf, true);
  return u.f;
}
#define QP_XOR1 177   // quad_perm [1,0,3,2]
#define QP_XOR2 78    // quad_perm [2,3,0,1]

// ---------------------------------------------------------------------------
// Prep: combined recurrent weights, bf16, block-permuted column order.
// Block nb owns gate-cols [nb*32, nb*32+32); n = nb*32 + nt*16 + rq*4 + gate,
// h-col j = nb*8 + 2*rq + nt. Rows k<1024 -> Wh, k>=1024 -> Wx.
// ---------------------------------------------------------------------------
__global__ void build_wc(const float* __restrict__ WhF, const float* __restrict__ WxF,
                         const float* __restrict__ WhB, const float* __restrict__ WxB,
                         u16* __restrict__ WcF, u16* __restrict__ WcB)
{
  const int z = blockIdx.z; const int dir = z >> 2, gate = z & 3;
  const float* Wh = dir ? WhB : WhF;
  const float* Wx = dir ? WxB : WxF;
  u16* Wc = dir ? WcB : WcF;
  const int k0 = blockIdx.x * 64, j0 = blockIdx.y * 64;
  __shared__ float tile[64][65];
  const int t = threadIdx.x;
  #pragma unroll
  for (int i = 0; i < 16; ++i) {
    int idx = i*256 + t; int kr = idx >> 6, jc = idx & 63;
    int k = k0 + kr;
    float v = (k < HID) ? Wh[(size_t)k*GDIM + gate*HID + j0 + jc]
                        : Wx[(size_t)(k-HID)*GDIM + gate*HID + j0 + jc];
    tile[kr][jc] = v;
  }
  __syncthreads();
  #pragma unroll
  for (int i = 0; i < 16; ++i) {
    int idx = i*256 + t; int jc = idx >> 6, kr = idx & 63;
    int j  = j0 + jc;
    int nb = j >> 3, jl = j & 7;
    int nt = jl & 1, rq = jl >> 1;
    int n  = nb*32 + nt*16 + rq*4 + gate;
    Wc[(size_t)n*KC + k0 + kr] = f2bf(tile[kr][jc]);
  }
}

__global__ void build_wfc(const float* __restrict__ Wfc, u16* __restrict__ WfcT)
{
  const int k0 = blockIdx.x * 64;
  const int n0 = blockIdx.y * 64;
  __shared__ float tile[64][65];
  const int t = threadIdx.x;
  #pragma unroll
  for (int i = 0; i < 16; ++i) {
    int idx = i*256 + t; int kr = idx >> 6, nc = idx & 63;
    tile[kr][nc] = Wfc[(size_t)(k0+kr)*OUTD + n0 + nc];
  }
  __syncthreads();
  #pragma unroll
  for (int i = 0; i < 16; ++i) {
    int idx = i*256 + t; int nc = idx >> 6, kr = idx & 63;
    WfcT[(size_t)(n0+nc)*2048 + k0 + kr] = f2bf(tile[kr][nc]);
  }
}

__global__ void conv_x(const float* __restrict__ x, u16* __restrict__ xb, int n)
{
  int i = (blockIdx.x * blockDim.x + threadIdx.x) * 4;
  if (i < n) {
    float4 v = *(const float4*)(x + i);
    u32 lo = (u32)f2bf(v.x) | ((u32)f2bf(v.y) << 16);
    u32 hi = (u32)f2bf(v.z) | ((u32)f2bf(v.w) << 16);
    *(uint2*)(xb + i) = make_uint2(lo, hi);
  }
}

// ---------------------------------------------------------------------------
// Persistent bidirectional LSTM (r9 + forced-batch h loads + post-poll x MFMAs).
// 256 blocks (128/dir), each owns 32 gate-cols (8 h-cols) for all 256 steps.
// B panel resident in 80KB LDS. c in registers. h history in hs (write-once
// per call): producers agent-store (sc1 -> IC); consumers flag-gated normal
// cached loads. Per-wave flags; no __syncthreads in the step loop.
// ---------------------------------------------------------------------------
__global__ __launch_bounds__(256, 1) void lstm_persist(
    const u16* __restrict__ WcF, const u16* __restrict__ WcB,
    const u16* __restrict__ xb,
    const float* __restrict__ bF, const float* __restrict__ bB,
    u16* __restrict__ hs, float* __restrict__ out_tail, int* flags)
{
  extern __shared__ __align__(16) u16 Bs[];   // [NSL][2][64][8]

  // one-time: clear stale lines (poison / previous replay) from L1/L2
  __builtin_amdgcn_fence(__ATOMIC_ACQUIRE, "agent");

  const int bid = blockIdx.x;
  const int dir = bid >> 7;
  const int nb  = bid & 127;
  const int n0  = nb * 32;
  const u16* __restrict__ Wc   = dir ? WcB : WcF;
  const float* __restrict__ bias = dir ? bB : bF;

  const int tid  = threadIdx.x;
  const int w    = tid >> 6, lane = tid & 63;
  const int r    = lane & 15, q = lane >> 4, rq = r >> 2;
  int* __restrict__ fl = flags + (dir * 4 + w) * DBLK;

  // stage B panel into LDS: chunk c -> [ks][nt][lane] 16B
  for (int c = tid; c < NSL * 128; c += 256) {
    int ks  = c >> 7;
    int rem = c & 127;
    int nt  = rem >> 6, l2 = rem & 63;
    *(short8*)&Bs[(size_t)c * 8] =
        *(const short8*)(Wc + (size_t)(n0 + nt*16 + (l2 & 15)) * KC + ks*32 + (l2 >> 4)*8);
  }
  #define BSF(ks, nt) (*(const short8*)&Bs[((size_t)(((ks)*2 + (nt))*64 + lane))*8])

  const int jbase = nb * 8;
  float bia[2][4];
  #pragma unroll
  for (int nt = 0; nt < 2; ++nt)
    #pragma unroll
    for (int g = 0; g < 4; ++g)
      bia[nt][g] = bias[g * HID + jbase + 2*rq + nt];

  float creg[2][4];
  #pragma unroll
  for (int nt = 0; nt < 2; ++nt)
    #pragma unroll
    for (int rg = 0; rg < 4; ++rg) creg[nt][rg] = 0.f;

  const int row_a = w * 16 + r;

  // prefetch x fragments for step 0
  short8 xf[8];
  {
    const int tt0 = dir ? (T_SEQ - 1) : 0;
    const u16* axr = xb + ((size_t)tt0 * BATCH + row_a) * INP;
    #pragma unroll
    for (int kx = 0; kx < 8; ++kx) xf[kx] = *(const short8*)(axr + kx*32 + q*8);
  }
  __syncthreads();   // Bs staged (only block-wide barrier)

  int pf0 = 0, pf1 = 0;   // primed flag values

  for (int s = 0; s < T_SEQ; ++s) {
    const int tt = dir ? (T_SEQ - 1 - s) : s;

    short8 hA[32];
    if (s > 0) {
      // wait for all wave-w producers of step s-1 (pf primed last iteration)
      while (!__all((pf0 >= s) && (pf1 >= s))) {
        pf0 = ag_ld_i32(fl + 2*lane);
        pf1 = ag_ld_i32(fl + 2*lane + 1);
      }
      const int tp = dir ? tt + 1 : tt - 1;
      const u16* __restrict__ ar =
          hs + ((size_t)tp * BATCH + row_a) * 2048 + dir * HID;
      #pragma unroll
      for (int i = 0; i < 32; ++i) hA[i] = *(const short8*)(ar + i*32 + q*8);
      // pin: all 32 loads issued as one batch, before any MFMA consumes them
      __builtin_amdgcn_sched_barrier(0);
    }

    // x-part MFMAs (xf loaded last iteration -> data arrived during poll);
    // they execute while the h-load batch is in flight.
    f32x4 accA[2], accB[2];
    accA[0] = (f32x4)(0.f); accA[1] = (f32x4)(0.f);
    accB[0] = (f32x4)(0.f); accB[1] = (f32x4)(0.f);
    #pragma unroll
    for (int kx = 0; kx < 8; ++kx) {
      accA[0] = MFMA16(xf[kx], BSF(32 + kx, 0), accA[0]);
      accA[1] = MFMA16(xf[kx], BSF(32 + kx, 1), accA[1]);
    }

    if (s > 0) {
      #pragma unroll
      for (int i = 0; i < 16; ++i) {
        accA[0] = MFMA16(hA[i], BSF(i, 0), accA[0]);
        accA[1] = MFMA16(hA[i], BSF(i, 1), accA[1]);
        accB[0] = MFMA16(hA[16 + i], BSF(16 + i, 0), accB[0]);
        accB[1] = MFMA16(hA[16 + i], BSF(16 + i, 1), accB[1]);
      }
    }

    // merge chains + cell update (DPP quad gather; gate = r&3)
    float hnv[2][4];
    #pragma unroll
    for (int nt = 0; nt < 2; ++nt) {
      #pragma unroll
      for (int rg = 0; rg < 4; ++rg) {
        float v  = accA[nt][rg] + accB[nt][rg];
        float x1 = qperm<QP_XOR1>(v);
        float x2 = qperm<QP_XOR2>(v);
        float x3 = qperm<QP_XOR2>(x1);
        float cn = sigm(x1 + bia[nt][1]) * creg[nt][rg] + sigm(v + bia[nt][0]) * tanhf_(x3 + bia[nt][3]);
        float hn = sigm(x2 + bia[nt][2]) * tanhf_(cn);
        creg[nt][rg] = cn; hnv[nt][rg] = hn;
      }
    }
    // packed u32 agent stores: writer lanes (r&3)==0 own cols (jbase+2rq, +1)
    if ((r & 3) == 0) {
      #pragma unroll
      for (int rg = 0; rg < 4; ++rg) {
        int row = w * 16 + q * 4 + rg;
        u32 packed = (u32)f2bf(hnv[0][rg]) | ((u32)f2bf(hnv[1][rg]) << 16);
        ag_st_u32((u32*)(hs + ((size_t)tt * BATCH + row) * 2048 + dir * HID + jbase + 2*rq),
                  packed);
      }
    }

    if (s < T_SEQ - 1) {
      asm volatile("s_waitcnt vmcnt(0)" ::: "memory");   // h stores at IC
      if (lane == 0) ag_st_u32((u32*)(fl + nb), (u32)(s + 1));
      // issue next step's x loads + prime flag loads: latency hides under poll
      const int tn = dir ? tt - 1 : tt + 1;
      const u16* axr = xb + ((size_t)tn * BATCH + row_a) * INP;
      #pragma unroll
      for (int kx = 0; kx < 8; ++kx) xf[kx] = *(const short8*)(axr + kx*32 + q*8);
      pf0 = ag_ld_i32(fl + 2*lane);
      pf1 = ag_ld_i32(fl + 2*lane + 1);
    } else {
      // final states ((hF,hB),(cF,cB)); plain stores (kernel-end flush)
      if ((r & 3) == 0) {
        #pragma unroll
        for (int nt = 0; nt < 2; ++nt)
          #pragma unroll
          for (int rg = 0; rg < 4; ++rg) {
            int row = w * 16 + q * 4 + rg;
            int j   = jbase + 2*rq + nt;
            out_tail[dir * (BATCH * HID) + (size_t)row * HID + j] = hnv[nt][rg];
            out_tail[2 * (BATCH * HID) + dir * (BATCH * HID) + (size_t)row * HID + j] = creg[nt][rg];
          }
      }
    }
  }
  #undef BSF
}

// ---------------------------------------------------------------------------
// Final FC: out[16384][1024] = hs[16384][2048] @ WfcT^T + b_fc, f32 out.
// ---------------------------------------------------------------------------
__global__ __launch_bounds__(256) void fc_kernel(
    const u16* __restrict__ hs, const u16* __restrict__ WfcT,
    const float* __restrict__ bfc, float* __restrict__ out)
{
  const int m0 = blockIdx.x * 128, n0 = blockIdx.y * 128;
  __shared__ __align__(16) u16 As[128 * 32];
  __shared__ __align__(16) u16 Bs[128 * 32];
  const int tid = threadIdx.x;
  const int w = tid >> 6, lane = tid & 63;
  const int r = lane & 15, q = lane >> 4;
  const int wy = w >> 1, wx = w & 1;

  f32x4 acc[4][4];
  #pragma unroll
  for (int a = 0; a < 4; ++a)
    #pragma unroll
    for (int b = 0; b < 4; ++b) acc[a][b] = (f32x4)(0.f);

  const int lr = tid >> 1, lk = (tid & 1) * 16;

  for (int k0 = 0; k0 < 2048; k0 += 32) {
    __syncthreads();
    *(short8*)&As[lr * 32 + lk]     = *(const short8*)(hs   + (size_t)(m0 + lr) * 2048 + k0 + lk);
    *(short8*)&As[lr * 32 + lk + 8] = *(const short8*)(hs   + (size_t)(m0 + lr) * 2048 + k0 + lk + 8);
    *(short8*)&Bs[lr * 32 + lk]     = *(const short8*)(WfcT + (size_t)(n0 + lr) * 2048 + k0 + lk);
    *(short8*)&Bs[lr * 32 + lk + 8] = *(const short8*)(WfcT + (size_t)(n0 + lr) * 2048 + k0 + lk + 8);
    __syncthreads();

    short8 af[4], bf[4];
    #pragma unroll
    for (int mt = 0; mt < 4; ++mt)
      af[mt] = *(const short8*)&As[(wy * 64 + mt * 16 + r) * 32 + q * 8];
    #pragma unroll
    for (int nt = 0; nt < 4; ++nt)
      bf[nt] = *(const short8*)&Bs[(wx * 64 + nt * 16 + r) * 32 + q * 8];
    #pragma unroll
    for (int mt = 0; mt < 4; ++mt)
      #pragma unroll
      for (int nt = 0; nt < 4; ++nt)
        acc[mt][nt] = __builtin_amdgcn_mfma_f32_16x16x32_bf16(af[mt], bf[nt], acc[mt][nt], 0, 0, 0);
  }

  #pragma unroll
  for (int mt = 0; mt < 4; ++mt)
    #pragma unroll
    for (int nt = 0; nt < 4; ++nt)
      #pragma unroll
      for (int reg = 0; reg < 4; ++reg) {
        int m = m0 + wy * 64 + mt * 16 + q * 4 + reg;
        int n = n0 + wx * 64 + nt * 16 + r;
        out[(size_t)m * OUTD + n] = acc[mt][nt][reg] + bfc[n];
      }
}

// ---------------------------------------------------------------------------
extern "C" void kernel_launch(void* const* d_in, const int* in_sizes, int n_in,
                              void* d_out, int out_size, void* d_ws, size_t ws_size,
                              hipStream_t stream)
{
  const float* x   = (const float*)d_in[0];
  const float* WxF = (const float*)d_in[1];
  const float* WhF = (const float*)d_in[2];
  const float* bF  = (const float*)d_in[3];
  const float* WxB = (const float*)d_in[4];
  const float* WhB = (const float*)d_in[5];
  const float* bB  = (const float*)d_in[6];
  const float* Wfc = (const float*)d_in[7];
  const float* bfc = (const float*)d_in[8];
  float* out = (float*)d_out;

  char* ws = (char*)d_ws;
  u16*  WcF   = (u16*)(ws + 0);          // 10485760
  u16*  WcB   = (u16*)(ws + 10485760);   // 10485760
  u16*  WfcT  = (u16*)(ws + 20971520);   // 4194304
  u16*  xb    = (u16*)(ws + 25165824);   // 8388608
  u16*  hs    = (u16*)(ws + 34603008);   // 67108864
  int*  flags = (int*)(ws + 101711872);  // 4KB (2 dirs x 4 waves x 128)

  hipMemsetAsync(flags, 0, 4096, stream);   // barrier flags

  hipFuncSetAttribute((const void*)lstm_persist,
                      hipFuncAttributeMaxDynamicSharedMemorySize, LDSB);

  build_wc <<<dim3(KC/64, HID/64, 8), 256, 0, stream>>>(WhF, WxF, WhB, WxB, WcF, WcB);
  build_wfc<<<dim3(2048/64, OUTD/64), 256, 0, stream>>>(Wfc, WfcT);
  conv_x   <<<(T_SEQ*BATCH*INP)/4/256, 256, 0, stream>>>(x, xb, T_SEQ*BATCH*INP);

  lstm_persist<<<NBLK, 256, LDSB, stream>>>(WcF, WcB, xb, bF, bB,
                                            hs, out + 16777216, flags);

  fc_kernel<<<dim3(16384/128, OUTD/128), 256, 0, stream>>>(hs, WfcT, bfc, out);
}

// Round 11
// 2942.719 us; speedup vs baseline: 1.0807x; 1.0807x over previous
//
#include <hip/hip_runtime.h>

using short8 = __attribute__((ext_vector_type(8))) short;
using f32x4  = __attribute__((ext_vector_type(4))) float;

typedef unsigned short u16;
typedef unsigned int   u32;
typedef unsigned long long u64;

#define T_SEQ 256
#define BATCH 64
#define INP   256
#define HID   1024
#define GDIM  4096
#define KC    1280   // HID + INP
#define OUTD  1024

#define NSL   40     // K slices of 32 (32 h + 8 x)
#define NBLK  256
#define DBLK  128    // blocks per direction
#define LDSB  (NSL * 2 * 64 * 8 * 2)   // 81920 bytes dynamic LDS

#define MFMA16(a,b,c) __builtin_amdgcn_mfma_f32_16x16x32_bf16(a,b,c,0,0,0)

__device__ __forceinline__ u16 f2bf(float f){
  union { float f; u32 u; } v; v.f = f;
  u32 r = v.u + 0x7fffu + ((v.u >> 16) & 1u);
  return (u16)(r >> 16);
}
__device__ __forceinline__ float sigm(float x){ return 1.f/(1.f+__expf(-x)); }
__device__ __forceinline__ float tanhf_(float x){ return 1.f - 2.f/(__expf(2.f*x)+1.f); }

// agent-scope (device-coherent, IC-resident) ops — compiler emits sc1
__device__ __forceinline__ void ag_st_u32(u32* p, u32 v){
  __hip_atomic_store(p, v, __ATOMIC_RELAXED, __HIP_MEMORY_SCOPE_AGENT);
}
__device__ __forceinline__ u64 ag_ld_u64(const u64* p){
  return __hip_atomic_load(p, __ATOMIC_RELAXED, __HIP_MEMORY_SCOPE_AGENT);
}

// quad-perm DPP: 4 gates of one h-col live in one lane-quad
template<int CTRL>
__device__ __forceinline__ float qperm(float v){
  union { float f; int i; } u; u.f = v;
  u.i = __builtin_amdgcn_mov_dpp(u.i, CTRL, 0xf, 0xf, true);
  return u.f;
}
#define QP_XOR1 177   // quad_perm [1,0,3,2]
#define QP_XOR2 78    // quad_perm [2,3,0,1]

// ---------------------------------------------------------------------------
// Prep: combined recurrent weights, bf16, block-permuted column order.
// Block nb owns gate-cols [nb*32, nb*32+32); n = nb*32 + nt*16 + rq*4 + gate,
// h-col j = nb*8 + 2*rq + nt. Rows k<1024 -> Wh, k>=1024 -> Wx.
// ---------------------------------------------------------------------------
__global__ void build_wc(const float* __restrict__ WhF, const float* __restrict__ WxF,
                         const float* __restrict__ WhB, const float* __restrict__ WxB,
                         u16* __restrict__ WcF, u16* __restrict__ WcB)
{
  const int z = blockIdx.z; const int dir = z >> 2, gate = z & 3;
  const float* Wh = dir ? WhB : WhF;
  const float* Wx = dir ? WxB : WxF;
  u16* Wc = dir ? WcB : WcF;
  const int k0 = blockIdx.x * 64, j0 = blockIdx.y * 64;
  __shared__ float tile[64][65];
  const int t = threadIdx.x;
  #pragma unroll
  for (int i = 0; i < 16; ++i) {
    int idx = i*256 + t; int kr = idx >> 6, jc = idx & 63;
    int k = k0 + kr;
    float v = (k < HID) ? Wh[(size_t)k*GDIM + gate*HID + j0 + jc]
                        : Wx[(size_t)(k-HID)*GDIM + gate*HID + j0 + jc];
    tile[kr][jc] = v;
  }
  __syncthreads();
  #pragma unroll
  for (int i = 0; i < 16; ++i) {
    int idx = i*256 + t; int jc = idx >> 6, kr = idx & 63;
    int j  = j0 + jc;
    int nb = j >> 3, jl = j & 7;
    int nt = jl & 1, rq = jl >> 1;
    int n  = nb*32 + nt*16 + rq*4 + gate;
    Wc[(size_t)n*KC + k0 + kr] = f2bf(tile[kr][jc]);
  }
}

__global__ void build_wfc(const float* __restrict__ Wfc, u16* __restrict__ WfcT)
{
  const int k0 = blockIdx.x * 64;
  const int n0 = blockIdx.y * 64;
  __shared__ float tile[64][65];
  const int t = threadIdx.x;
  #pragma unroll
  for (int i = 0; i < 16; ++i) {
    int idx = i*256 + t; int kr = idx >> 6, nc = idx & 63;
    tile[kr][nc] = Wfc[(size_t)(k0+kr)*OUTD + n0 + nc];
  }
  __syncthreads();
  #pragma unroll
  for (int i = 0; i < 16; ++i) {
    int idx = i*256 + t; int nc = idx >> 6, kr = idx & 63;
    WfcT[(size_t)(n0+nc)*2048 + k0 + kr] = f2bf(tile[kr][nc]);
  }
}

__global__ void conv_x(const float* __restrict__ x, u16* __restrict__ xb, int n)
{
  int i = (blockIdx.x * blockDim.x + threadIdx.x) * 4;
  if (i < n) {
    float4 v = *(const float4*)(x + i);
    u32 lo = (u32)f2bf(v.x) | ((u32)f2bf(v.y) << 16);
    u32 hi = (u32)f2bf(v.z) | ((u32)f2bf(v.w) << 16);
    *(uint2*)(xb + i) = make_uint2(lo, hi);
  }
}

// ---------------------------------------------------------------------------
// Persistent bidirectional LSTM (r9 champion + poll backoff + load batching).
// 256 blocks (128/dir), each owns 32 gate-cols (8 h-cols) for all 256 steps.
// B panel resident in 80KB LDS. c in registers. h history in hs (write-once
// per call): producers agent-store (sc1 -> IC); consumers flag-gated normal
// cached loads. Per-wave flags; no __syncthreads in the step loop.
// ---------------------------------------------------------------------------
__global__ __launch_bounds__(256, 1) void lstm_persist(
    const u16* __restrict__ WcF, const u16* __restrict__ WcB,
    const u16* __restrict__ xb,
    const float* __restrict__ bF, const float* __restrict__ bB,
    u16* __restrict__ hs, float* __restrict__ out_tail, int* flags)
{
  extern __shared__ __align__(16) u16 Bs[];   // [NSL][2][64][8]

  // one-time: clear stale lines (poison / previous replay) from L1/L2
  __builtin_amdgcn_fence(__ATOMIC_ACQUIRE, "agent");

  const int bid = blockIdx.x;
  const int dir = bid >> 7;
  const int nb  = bid & 127;
  const int n0  = nb * 32;
  const u16* __restrict__ Wc   = dir ? WcB : WcF;
  const float* __restrict__ bias = dir ? bB : bF;

  const int tid  = threadIdx.x;
  const int w    = tid >> 6, lane = tid & 63;
  const int r    = lane & 15, q = lane >> 4, rq = r >> 2;
  int* __restrict__ fl = flags + (dir * 4 + w) * DBLK;
  const u64* __restrict__ fl64 = (const u64*)fl;

  // stage B panel into LDS: chunk c -> [ks][nt][lane] 16B
  for (int c = tid; c < NSL * 128; c += 256) {
    int ks  = c >> 7;
    int rem = c & 127;
    int nt  = rem >> 6, l2 = rem & 63;
    *(short8*)&Bs[(size_t)c * 8] =
        *(const short8*)(Wc + (size_t)(n0 + nt*16 + (l2 & 15)) * KC + ks*32 + (l2 >> 4)*8);
  }
  #define BSF(ks, nt) (*(const short8*)&Bs[((size_t)(((ks)*2 + (nt))*64 + lane))*8])

  const int jbase = nb * 8;
  float bia[2][4];
  #pragma unroll
  for (int nt = 0; nt < 2; ++nt)
    #pragma unroll
    for (int g = 0; g < 4; ++g)
      bia[nt][g] = bias[g * HID + jbase + 2*rq + nt];

  float creg[2][4];
  #pragma unroll
  for (int nt = 0; nt < 2; ++nt)
    #pragma unroll
    for (int rg = 0; rg < 4; ++rg) creg[nt][rg] = 0.f;

  const int row_a = w * 16 + r;

  // prefetch x fragments for step 0
  short8 xf[8];
  {
    const int tt0 = dir ? (T_SEQ - 1) : 0;
    const u16* axr = xb + ((size_t)tt0 * BATCH + row_a) * INP;
    #pragma unroll
    for (int kx = 0; kx < 8; ++kx) xf[kx] = *(const short8*)(axr + kx*32 + q*8);
  }
  __syncthreads();   // Bs staged (only block-wide barrier)

  // x-part MFMAs of step 0 (r9 structure: tail-issued before each poll)
  f32x4 accA[2], accB[2];
  accA[0] = (f32x4)(0.f); accA[1] = (f32x4)(0.f);
  accB[0] = (f32x4)(0.f); accB[1] = (f32x4)(0.f);
  #pragma unroll
  for (int kx = 0; kx < 8; ++kx) {
    accA[0] = MFMA16(xf[kx], BSF(32 + kx, 0), accA[0]);
    accA[1] = MFMA16(xf[kx], BSF(32 + kx, 1), accA[1]);
  }

  u64 pf = 0;   // primed 64-bit flag-pair value

  for (int s = 0; s < T_SEQ; ++s) {
    const int tt = dir ? (T_SEQ - 1 - s) : s;

    if (s > 0) {
      // wait for all wave-w producers of step s-1; backoff between iterations
      while (true) {
        int ok = ((int)(pf & 0xffffffffu) >= s) && ((int)(pf >> 32) >= s);
        if (__all(ok)) break;
        __builtin_amdgcn_s_sleep(1);                 // ~64cy backoff: IC relief
        pf = ag_ld_u64(fl64 + lane);
      }
      const int tp = dir ? tt + 1 : tt - 1;
      const u16* __restrict__ ar =
          hs + ((size_t)tp * BATCH + row_a) * 2048 + dir * HID;
      short8 hA[32];
      #pragma unroll
      for (int i = 0; i < 32; ++i) hA[i] = *(const short8*)(ar + i*32 + q*8);
      // schedule hint: all 32 loads issue as one window, then the 64 MFMAs
      __builtin_amdgcn_sched_group_barrier(0x20, 32, 0);  // VMEM_READ x32
      #pragma unroll
      for (int i = 0; i < 16; ++i) {
        accA[0] = MFMA16(hA[i], BSF(i, 0), accA[0]);
        accA[1] = MFMA16(hA[i], BSF(i, 1), accA[1]);
        accB[0] = MFMA16(hA[16 + i], BSF(16 + i, 0), accB[0]);
        accB[1] = MFMA16(hA[16 + i], BSF(16 + i, 1), accB[1]);
      }
      __builtin_amdgcn_sched_group_barrier(0x8, 64, 0);   // MFMA x64
    }

    // merge chains + cell update (DPP quad gather; gate = r&3)
    float hnv[2][4];
    #pragma unroll
    for (int nt = 0; nt < 2; ++nt) {
      #pragma unroll
      for (int rg = 0; rg < 4; ++rg) {
        float v  = accA[nt][rg] + accB[nt][rg];
        float x1 = qperm<QP_XOR1>(v);
        float x2 = qperm<QP_XOR2>(v);
        float x3 = qperm<QP_XOR2>(x1);
        float cn = sigm(x1 + bia[nt][1]) * creg[nt][rg] + sigm(v + bia[nt][0]) * tanhf_(x3 + bia[nt][3]);
        float hn = sigm(x2 + bia[nt][2]) * tanhf_(cn);
        creg[nt][rg] = cn; hnv[nt][rg] = hn;
      }
    }
    // packed u32 agent stores: writer lanes (r&3)==0 own cols (jbase+2rq, +1)
    if ((r & 3) == 0) {
      #pragma unroll
      for (int rg = 0; rg < 4; ++rg) {
        int row = w * 16 + q * 4 + rg;
        u32 packed = (u32)f2bf(hnv[0][rg]) | ((u32)f2bf(hnv[1][rg]) << 16);
        ag_st_u32((u32*)(hs + ((size_t)tt * BATCH + row) * 2048 + dir * HID + jbase + 2*rq),
                  packed);
      }
    }

    if (s < T_SEQ - 1) {
      asm volatile("s_waitcnt vmcnt(0)" ::: "memory");   // h stores at IC
      if (lane == 0) ag_st_u32((u32*)(fl + nb), (u32)(s + 1));
      // issue next step's x loads + x-MFMAs + prime flag load (r9 tail):
      // their latency overlaps the flag propagation of other blocks.
      const int tn = dir ? tt - 1 : tt + 1;
      const u16* axr = xb + ((size_t)tn * BATCH + row_a) * INP;
      #pragma unroll
      for (int kx = 0; kx < 8; ++kx) xf[kx] = *(const short8*)(axr + kx*32 + q*8);
      pf = ag_ld_u64(fl64 + lane);
      accA[0] = (f32x4)(0.f); accA[1] = (f32x4)(0.f);
      accB[0] = (f32x4)(0.f); accB[1] = (f32x4)(0.f);
      #pragma unroll
      for (int kx = 0; kx < 8; ++kx) {
        accA[0] = MFMA16(xf[kx], BSF(32 + kx, 0), accA[0]);
        accA[1] = MFMA16(xf[kx], BSF(32 + kx, 1), accA[1]);
      }
    } else {
      // final states ((hF,hB),(cF,cB)); plain stores (kernel-end flush)
      if ((r & 3) == 0) {
        #pragma unroll
        for (int nt = 0; nt < 2; ++nt)
          #pragma unroll
          for (int rg = 0; rg < 4; ++rg) {
            int row = w * 16 + q * 4 + rg;
            int j   = jbase + 2*rq + nt;
            out_tail[dir * (BATCH * HID) + (size_t)row * HID + j] = hnv[nt][rg];
            out_tail[2 * (BATCH * HID) + dir * (BATCH * HID) + (size_t)row * HID + j] = creg[nt][rg];
          }
      }
    }
  }
  #undef BSF
}

// ---------------------------------------------------------------------------
// Final FC: out[16384][1024] = hs[16384][2048] @ WfcT^T + b_fc, f32 out.
// ---------------------------------------------------------------------------
__global__ __launch_bounds__(256) void fc_kernel(
    const u16* __restrict__ hs, const u16* __restrict__ WfcT,
    const float* __restrict__ bfc, float* __restrict__ out)
{
  const int m0 = blockIdx.x * 128, n0 = blockIdx.y * 128;
  __shared__ __align__(16) u16 As[128 * 32];
  __shared__ __align__(16) u16 Bs[128 * 32];
  const int tid = threadIdx.x;
  const int w = tid >> 6, lane = tid & 63;
  const int r = lane & 15, q = lane >> 4;
  const int wy = w >> 1, wx = w & 1;

  f32x4 acc[4][4];
  #pragma unroll
  for (int a = 0; a < 4; ++a)
    #pragma unroll
    for (int b = 0; b < 4; ++b) acc[a][b] = (f32x4)(0.f);

  const int lr = tid >> 1, lk = (tid & 1) * 16;

  for (int k0 = 0; k0 < 2048; k0 += 32) {
    __syncthreads();
    *(short8*)&As[lr * 32 + lk]     = *(const short8*)(hs   + (size_t)(m0 + lr) * 2048 + k0 + lk);
    *(short8*)&As[lr * 32 + lk + 8] = *(const short8*)(hs   + (size_t)(m0 + lr) * 2048 + k0 + lk + 8);
    *(short8*)&Bs[lr * 32 + lk]     = *(const short8*)(WfcT + (size_t)(n0 + lr) * 2048 + k0 + lk);
    *(short8*)&Bs[lr * 32 + lk + 8] = *(const short8*)(WfcT + (size_t)(n0 + lr) * 2048 + k0 + lk + 8);
    __syncthreads();

    short8 af[4], bf[4];
    #pragma unroll
    for (int mt = 0; mt < 4; ++mt)
      af[mt] = *(const short8*)&As[(wy * 64 + mt * 16 + r) * 32 + q * 8];
    #pragma unroll
    for (int nt = 0; nt < 4; ++nt)
      bf[nt] = *(const short8*)&Bs[(wx * 64 + nt * 16 + r) * 32 + q * 8];
    #pragma unroll
    for (int mt = 0; mt < 4; ++mt)
      #pragma unroll
      for (int nt = 0; nt < 4; ++nt)
        acc[mt][nt] = __builtin_amdgcn_mfma_f32_16x16x32_bf16(af[mt], bf[nt], acc[mt][nt], 0, 0, 0);
  }

  #pragma unroll
  for (int mt = 0; mt < 4; ++mt)
    #pragma unroll
    for (int nt = 0; nt < 4; ++nt)
      #pragma unroll
      for (int reg = 0; reg < 4; ++reg) {
        int m = m0 + wy * 64 + mt * 16 + q * 4 + reg;
        int n = n0 + wx * 64 + nt * 16 + r;
        out[(size_t)m * OUTD + n] = acc[mt][nt][reg] + bfc[n];
      }
}

// ---------------------------------------------------------------------------
extern "C" void kernel_launch(void* const* d_in, const int* in_sizes, int n_in,
                              void* d_out, int out_size, void* d_ws, size_t ws_size,
                              hipStream_t stream)
{
  const float* x   = (const float*)d_in[0];
  const float* WxF = (const float*)d_in[1];
  const float* WhF = (const float*)d_in[2];
  const float* bF  = (const float*)d_in[3];
  const float* WxB = (const float*)d_in[4];
  const float* WhB = (const float*)d_in[5];
  const float* bB  = (const float*)d_in[6];
  const float* Wfc = (const float*)d_in[7];
  const float* bfc = (const float*)d_in[8];
  float* out = (float*)d_out;

  char* ws = (char*)d_ws;
  u16*  WcF   = (u16*)(ws + 0);          // 10485760
  u16*  WcB   = (u16*)(ws + 10485760);   // 10485760
  u16*  WfcT  = (u16*)(ws + 20971520);   // 4194304
  u16*  xb    = (u16*)(ws + 25165824);   // 8388608
  u16*  hs    = (u16*)(ws + 34603008);   // 67108864
  int*  flags = (int*)(ws + 101711872);  // 4KB (2 dirs x 4 waves x 128)

  hipMemsetAsync(flags, 0, 4096, stream);   // barrier flags

  hipFuncSetAttribute((const void*)lstm_persist,
                      hipFuncAttributeMaxDynamicSharedMemorySize, LDSB);

  build_wc <<<dim3(KC/64, HID/64, 8), 256, 0, stream>>>(WhF, WxF, WhB, WxB, WcF, WcB);
  build_wfc<<<dim3(2048/64, OUTD/64), 256, 0, stream>>>(Wfc, WfcT);
  conv_x   <<<(T_SEQ*BATCH*INP)/4/256, 256, 0, stream>>>(x, xb, T_SEQ*BATCH*INP);

  lstm_persist<<<NBLK, 256, LDSB, stream>>>(WcF, WcB, xb, bF, bB,
                                            hs, out + 16777216, flags);

  fc_kernel<<<dim3(16384/128, OUTD/128), 256, 0, stream>>>(hs, WfcT, bfc, out);
}

// Round 12
// 2410.064 us; speedup vs baseline: 1.3196x; 1.2210x over previous
//
#include <hip/hip_runtime.h>

using short8 = __attribute__((ext_vector_type(8))) short;
using f32x4  = __attribute__((ext_vector_type(4))) float;

typedef unsigned short u16;
typedef unsigned int   u32;
typedef unsigned long long u64;

#define T_SEQ 256
#define BATCH 64
#define INP   256
#define HID   1024
#define GDIM  4096
#define KC    1280   // HID + INP
#define OUTD  1024

#define NSL   40     // K slices of 32 (32 h + 8 x)
#define NBLK  256
#define DBLK  128    // blocks per direction
#define LDSB  (NSL * 2 * 64 * 8 * 2)   // 81920 bytes dynamic LDS

#define MFMA16(a,b,c) __builtin_amdgcn_mfma_f32_16x16x32_bf16(a,b,c,0,0,0)

__device__ __forceinline__ u16 f2bf(float f){
  union { float f; u32 u; } v; v.f = f;
  u32 r = v.u + 0x7fffu + ((v.u >> 16) & 1u);
  return (u16)(r >> 16);
}
__device__ __forceinline__ float sigm(float x){ return 1.f/(1.f+__expf(-x)); }
__device__ __forceinline__ float tanhf_(float x){ return 1.f - 2.f/(__expf(2.f*x)+1.f); }

// agent-scope (device-coherent, IC-resident) ops — compiler emits sc1
__device__ __forceinline__ void ag_st_u32(u32* p, u32 v){
  __hip_atomic_store(p, v, __ATOMIC_RELAXED, __HIP_MEMORY_SCOPE_AGENT);
}
__device__ __forceinline__ u64 ag_ld_u64(const u64* p){
  return __hip_atomic_load(p, __ATOMIC_RELAXED, __HIP_MEMORY_SCOPE_AGENT);
}

// quad-perm DPP: 4 gates of one h-col live in one lane-quad
template<int CTRL>
__device__ __forceinline__ float qperm(float v){
  union { float f; int i; } u; u.f = v;
  u.i = __builtin_amdgcn_mov_dpp(u.i, CTRL, 0xf, 0xf, true);
  return u.f;
}
#define QP_XOR1 177   // quad_perm [1,0,3,2]
#define QP_XOR2 78    // quad_perm [2,3,0,1]

// ---------------------------------------------------------------------------
// Prep: combined recurrent weights, bf16, block-permuted column order.
// Block nb owns gate-cols [nb*32, nb*32+32); n = nb*32 + nt*16 + rq*4 + gate,
// h-col j = nb*8 + 2*rq + nt. Rows k<1024 -> Wh, k>=1024 -> Wx.
// ---------------------------------------------------------------------------
__global__ void build_wc(const float* __restrict__ WhF, const float* __restrict__ WxF,
                         const float* __restrict__ WhB, const float* __restrict__ WxB,
                         u16* __restrict__ WcF, u16* __restrict__ WcB)
{
  const int z = blockIdx.z; const int dir = z >> 2, gate = z & 3;
  const float* Wh = dir ? WhB : WhF;
  const float* Wx = dir ? WxB : WxF;
  u16* Wc = dir ? WcB : WcF;
  const int k0 = blockIdx.x * 64, j0 = blockIdx.y * 64;
  __shared__ float tile[64][65];
  const int t = threadIdx.x;
  #pragma unroll
  for (int i = 0; i < 16; ++i) {
    int idx = i*256 + t; int kr = idx >> 6, jc = idx & 63;
    int k = k0 + kr;
    float v = (k < HID) ? Wh[(size_t)k*GDIM + gate*HID + j0 + jc]
                        : Wx[(size_t)(k-HID)*GDIM + gate*HID + j0 + jc];
    tile[kr][jc] = v;
  }
  __syncthreads();
  #pragma unroll
  for (int i = 0; i < 16; ++i) {
    int idx = i*256 + t; int jc = idx >> 6, kr = idx & 63;
    int j  = j0 + jc;
    int nb = j >> 3, jl = j & 7;
    int nt = jl & 1, rq = jl >> 1;
    int n  = nb*32 + nt*16 + rq*4 + gate;
    Wc[(size_t)n*KC + k0 + kr] = f2bf(tile[kr][jc]);
  }
}

__global__ void build_wfc(const float* __restrict__ Wfc, u16* __restrict__ WfcT)
{
  const int k0 = blockIdx.x * 64;
  const int n0 = blockIdx.y * 64;
  __shared__ float tile[64][65];
  const int t = threadIdx.x;
  #pragma unroll
  for (int i = 0; i < 16; ++i) {
    int idx = i*256 + t; int kr = idx >> 6, nc = idx & 63;
    tile[kr][nc] = Wfc[(size_t)(k0+kr)*OUTD + n0 + nc];
  }
  __syncthreads();
  #pragma unroll
  for (int i = 0; i < 16; ++i) {
    int idx = i*256 + t; int nc = idx >> 6, kr = idx & 63;
    WfcT[(size_t)(n0+nc)*2048 + k0 + kr] = f2bf(tile[kr][nc]);
  }
}

__global__ void conv_x(const float* __restrict__ x, u16* __restrict__ xb, int n)
{
  int i = (blockIdx.x * blockDim.x + threadIdx.x) * 4;
  if (i < n) {
    float4 v = *(const float4*)(x + i);
    u32 lo = (u32)f2bf(v.x) | ((u32)f2bf(v.y) << 16);
    u32 hi = (u32)f2bf(v.z) | ((u32)f2bf(v.w) << 16);
    *(uint2*)(xb + i) = make_uint2(lo, hi);
  }
}

// ---------------------------------------------------------------------------
// Persistent bidirectional LSTM (r9 champion + block-contiguous h layout).
// hs2[t][dir][nb][row 0..63][8 cols] (u32 = 2 bf16 cols): each block's step
// output is ONE contiguous 1KB region (16 cache lines vs 64 scattered) ->
// faster store drain, better consumer line locality. A-fragment for K-slice
// ks: lane (r,q) reads block 4ks+q's 8 cols of its row = one dwordx4.
// ---------------------------------------------------------------------------
__global__ __launch_bounds__(256, 1) void lstm_persist(
    const u16* __restrict__ WcF, const u16* __restrict__ WcB,
    const u16* __restrict__ xb,
    const float* __restrict__ bF, const float* __restrict__ bB,
    u32* __restrict__ hs2, float* __restrict__ out_tail, int* flags)
{
  extern __shared__ __align__(16) u16 Bs[];   // [NSL][2][64][8]

  // one-time: clear stale lines (poison / previous replay) from L1/L2
  __builtin_amdgcn_fence(__ATOMIC_ACQUIRE, "agent");

  const int bid = blockIdx.x;
  const int dir = bid >> 7;
  const int nb  = bid & 127;
  const int n0  = nb * 32;
  const u16* __restrict__ Wc   = dir ? WcB : WcF;
  const float* __restrict__ bias = dir ? bB : bF;

  const int tid  = threadIdx.x;
  const int w    = tid >> 6, lane = tid & 63;
  const int r    = lane & 15, q = lane >> 4, rq = r >> 2;
  int* __restrict__ fl = flags + (dir * 4 + w) * DBLK;
  const u64* __restrict__ fl64 = (const u64*)fl;

  // stage B panel into LDS: chunk c -> [ks][nt][lane] 16B
  for (int c = tid; c < NSL * 128; c += 256) {
    int ks  = c >> 7;
    int rem = c & 127;
    int nt  = rem >> 6, l2 = rem & 63;
    *(short8*)&Bs[(size_t)c * 8] =
        *(const short8*)(Wc + (size_t)(n0 + nt*16 + (l2 & 15)) * KC + ks*32 + (l2 >> 4)*8);
  }
  #define BSF(ks, nt) (*(const short8*)&Bs[((size_t)(((ks)*2 + (nt))*64 + lane))*8])

  const int jbase = nb * 8;
  float bia[2][4];
  #pragma unroll
  for (int nt = 0; nt < 2; ++nt)
    #pragma unroll
    for (int g = 0; g < 4; ++g)
      bia[nt][g] = bias[g * HID + jbase + 2*rq + nt];

  float creg[2][4];
  #pragma unroll
  for (int nt = 0; nt < 2; ++nt)
    #pragma unroll
    for (int rg = 0; rg < 4; ++rg) creg[nt][rg] = 0.f;

  const int row_a = w * 16 + r;

  // prefetch x fragments for step 0
  short8 xf[8];
  {
    const int tt0 = dir ? (T_SEQ - 1) : 0;
    const u16* axr = xb + ((size_t)tt0 * BATCH + row_a) * INP;
    #pragma unroll
    for (int kx = 0; kx < 8; ++kx) xf[kx] = *(const short8*)(axr + kx*32 + q*8);
  }
  __syncthreads();   // Bs staged (only block-wide barrier)

  // x-part MFMAs of step 0 (tail-issued structure)
  f32x4 accA[2], accB[2];
  accA[0] = (f32x4)(0.f); accA[1] = (f32x4)(0.f);
  accB[0] = (f32x4)(0.f); accB[1] = (f32x4)(0.f);
  #pragma unroll
  for (int kx = 0; kx < 8; ++kx) {
    accA[0] = MFMA16(xf[kx], BSF(32 + kx, 0), accA[0]);
    accA[1] = MFMA16(xf[kx], BSF(32 + kx, 1), accA[1]);
  }

  u64 pf = 0;   // primed 64-bit flag-pair value

  for (int s = 0; s < T_SEQ; ++s) {
    const int tt = dir ? (T_SEQ - 1 - s) : s;

    if (s > 0) {
      // wait for all wave-w producers of step s-1 (pf primed last iteration)
      while (true) {
        int ok = ((int)(pf & 0xffffffffu) >= s) && ((int)(pf >> 32) >= s);
        if (__all(ok)) break;
        pf = ag_ld_u64(fl64 + lane);
      }
      const int tp = dir ? tt + 1 : tt - 1;
      // A-fragment base: block q of each slice-group, this lane's row
      const u32* __restrict__ ar =
          hs2 + (((size_t)(tp * 2 + dir) * 128 + q) * 64 + row_a) * 4;
      short8 hA[32];
      #pragma unroll
      for (int i = 0; i < 32; ++i)
        hA[i] = *(const short8*)(ar + (size_t)i * 1024);   // +4 blocks/slice
      #pragma unroll
      for (int i = 0; i < 16; ++i) {
        accA[0] = MFMA16(hA[i], BSF(i, 0), accA[0]);
        accA[1] = MFMA16(hA[i], BSF(i, 1), accA[1]);
        accB[0] = MFMA16(hA[16 + i], BSF(16 + i, 0), accB[0]);
        accB[1] = MFMA16(hA[16 + i], BSF(16 + i, 1), accB[1]);
      }
    }

    // merge chains + cell update (DPP quad gather; gate = r&3)
    float hnv[2][4];
    #pragma unroll
    for (int nt = 0; nt < 2; ++nt) {
      #pragma unroll
      for (int rg = 0; rg < 4; ++rg) {
        float v  = accA[nt][rg] + accB[nt][rg];
        float x1 = qperm<QP_XOR1>(v);
        float x2 = qperm<QP_XOR2>(v);
        float x3 = qperm<QP_XOR2>(x1);
        float cn = sigm(x1 + bia[nt][1]) * creg[nt][rg] + sigm(v + bia[nt][0]) * tanhf_(x3 + bia[nt][3]);
        float hn = sigm(x2 + bia[nt][2]) * tanhf_(cn);
        creg[nt][rg] = cn; hnv[nt][rg] = hn;
      }
    }
    // packed u32 agent stores into the block-contiguous region:
    // hs2[tt][dir][nb][row = w*16+q*4+rg][colpair rq]
    if ((r & 3) == 0) {
      u32* base = hs2 + (((size_t)(tt * 2 + dir) * 128 + nb) * 64 + w*16 + q*4) * 4 + rq;
      #pragma unroll
      for (int rg = 0; rg < 4; ++rg) {
        u32 packed = (u32)f2bf(hnv[0][rg]) | ((u32)f2bf(hnv[1][rg]) << 16);
        ag_st_u32(base + rg * 4, packed);
      }
    }

    if (s < T_SEQ - 1) {
      asm volatile("s_waitcnt vmcnt(0)" ::: "memory");   // h stores at IC
      if (lane == 0) ag_st_u32((u32*)(fl + nb), (u32)(s + 1));
      // issue next step's x loads + prime flag load + x-MFMAs (r9 tail):
      // their latency overlaps the flag propagation of other blocks.
      const int tn = dir ? tt - 1 : tt + 1;
      const u16* axr = xb + ((size_t)tn * BATCH + row_a) * INP;
      #pragma unroll
      for (int kx = 0; kx < 8; ++kx) xf[kx] = *(const short8*)(axr + kx*32 + q*8);
      pf = ag_ld_u64(fl64 + lane);
      accA[0] = (f32x4)(0.f); accA[1] = (f32x4)(0.f);
      accB[0] = (f32x4)(0.f); accB[1] = (f32x4)(0.f);
      #pragma unroll
      for (int kx = 0; kx < 8; ++kx) {
        accA[0] = MFMA16(xf[kx], BSF(32 + kx, 0), accA[0]);
        accA[1] = MFMA16(xf[kx], BSF(32 + kx, 1), accA[1]);
      }
    } else {
      // final states ((hF,hB),(cF,cB)); plain stores (kernel-end flush)
      if ((r & 3) == 0) {
        #pragma unroll
        for (int nt = 0; nt < 2; ++nt)
          #pragma unroll
          for (int rg = 0; rg < 4; ++rg) {
            int row = w * 16 + q * 4 + rg;
            int j   = jbase + 2*rq + nt;
            out_tail[dir * (BATCH * HID) + (size_t)row * HID + j] = hnv[nt][rg];
            out_tail[2 * (BATCH * HID) + dir * (BATCH * HID) + (size_t)row * HID + j] = creg[nt][rg];
          }
      }
    }
  }
  #undef BSF
}

// ---------------------------------------------------------------------------
// Final FC: out[16384][1024] = H @ WfcT^T + b_fc, H read from hs2 layout.
// hs2[t][dir][nb][row][4 u32]: k = dir*1024 + nb*8 + c.
// ---------------------------------------------------------------------------
__global__ __launch_bounds__(256) void fc_kernel(
    const u32* __restrict__ hs2, const u16* __restrict__ WfcT,
    const float* __restrict__ bfc, float* __restrict__ out)
{
  const int m0 = blockIdx.x * 128, n0 = blockIdx.y * 128;
  __shared__ __align__(16) u16 As[128 * 32];
  __shared__ __align__(16) u16 Bs[128 * 32];
  const int tid = threadIdx.x;
  const int w = tid >> 6, lane = tid & 63;
  const int r = lane & 15, q = lane >> 4;
  const int wy = w >> 1, wx = w & 1;

  f32x4 acc[4][4];
  #pragma unroll
  for (int a = 0; a < 4; ++a)
    #pragma unroll
    for (int b = 0; b < 4; ++b) acc[a][b] = (f32x4)(0.f);

  const int lr = tid >> 1, lk = (tid & 1) * 16;

  for (int k0 = 0; k0 < 2048; k0 += 32) {
    __syncthreads();
    {
      int m = m0 + lr; int t = m >> 6, row = m & 63;
      int k = k0 + lk; int d = k >> 10, kk = k & 1023; int nb2 = kk >> 3;
      const u32* p = hs2 + (((size_t)(t * 2 + d) * 128 + nb2) * 64 + row) * 4;
      *(short8*)&As[lr * 32 + lk]     = *(const short8*)p;
      *(short8*)&As[lr * 32 + lk + 8] = *(const short8*)(p + 256);  // nb2+1
    }
    *(short8*)&Bs[lr * 32 + lk]     = *(const short8*)(WfcT + (size_t)(n0 + lr) * 2048 + k0 + lk);
    *(short8*)&Bs[lr * 32 + lk + 8] = *(const short8*)(WfcT + (size_t)(n0 + lr) * 2048 + k0 + lk + 8);
    __syncthreads();

    short8 af[4], bf[4];
    #pragma unroll
    for (int mt = 0; mt < 4; ++mt)
      af[mt] = *(const short8*)&As[(wy * 64 + mt * 16 + r) * 32 + q * 8];
    #pragma unroll
    for (int nt = 0; nt < 4; ++nt)
      bf[nt] = *(const short8*)&Bs[(wx * 64 + nt * 16 + r) * 32 + q * 8];
    #pragma unroll
    for (int mt = 0; mt < 4; ++mt)
      #pragma unroll
      for (int nt = 0; nt < 4; ++nt)
        acc[mt][nt] = __builtin_amdgcn_mfma_f32_16x16x32_bf16(af[mt], bf[nt], acc[mt][nt], 0, 0, 0);
  }

  #pragma unroll
  for (int mt = 0; mt < 4; ++mt)
    #pragma unroll
    for (int nt = 0; nt < 4; ++nt)
      #pragma unroll
      for (int reg = 0; reg < 4; ++reg) {
        int m = m0 + wy * 64 + mt * 16 + q * 4 + reg;
        int n = n0 + wx * 64 + nt * 16 + r;
        out[(size_t)m * OUTD + n] = acc[mt][nt][reg] + bfc[n];
      }
}

// ---------------------------------------------------------------------------
extern "C" void kernel_launch(void* const* d_in, const int* in_sizes, int n_in,
                              void* d_out, int out_size, void* d_ws, size_t ws_size,
                              hipStream_t stream)
{
  const float* x   = (const float*)d_in[0];
  const float* WxF = (const float*)d_in[1];
  const float* WhF = (const float*)d_in[2];
  const float* bF  = (const float*)d_in[3];
  const float* WxB = (const float*)d_in[4];
  const float* WhB = (const float*)d_in[5];
  const float* bB  = (const float*)d_in[6];
  const float* Wfc = (const float*)d_in[7];
  const float* bfc = (const float*)d_in[8];
  float* out = (float*)d_out;

  char* ws = (char*)d_ws;
  u16*  WcF   = (u16*)(ws + 0);          // 10485760
  u16*  WcB   = (u16*)(ws + 10485760);   // 10485760
  u16*  WfcT  = (u16*)(ws + 20971520);   // 4194304
  u16*  xb    = (u16*)(ws + 25165824);   // 8388608
  u32*  hs2   = (u32*)(ws + 34603008);   // 67108864 (t,dir,nb,row,4xu32)
  int*  flags = (int*)(ws + 101711872);  // 4KB (2 dirs x 4 waves x 128)

  hipMemsetAsync(flags, 0, 4096, stream);   // barrier flags

  hipFuncSetAttribute((const void*)lstm_persist,
                      hipFuncAttributeMaxDynamicSharedMemorySize, LDSB);

  build_wc <<<dim3(KC/64, HID/64, 8), 256, 0, stream>>>(WhF, WxF, WhB, WxB, WcF, WcB);
  build_wfc<<<dim3(2048/64, OUTD/64), 256, 0, stream>>>(Wfc, WfcT);
  conv_x   <<<(T_SEQ*BATCH*INP)/4/256, 256, 0, stream>>>(x, xb, T_SEQ*BATCH*INP);

  lstm_persist<<<NBLK, 256, LDSB, stream>>>(WcF, WcB, xb, bF, bB,
                                            hs2, out + 16777216, flags);

  fc_kernel<<<dim3(16384/128, OUTD/128), 256, 0, stream>>>(hs2, WfcT, bfc, out);
}